// Round 3
// baseline (67.686 us; speedup 1.0000x reference)
//
#include <hip/hip_runtime.h>
#include <math.h>

// Match numpy/XLA fp32 semantics: no compiler-introduced FMA contraction.
#pragma clang fp contract(off)

#define KCAP 64             // output neighbor cap (reference K)
#define QPW 8               // queries per wave (each LDS point read feeds 8 pairs)
#define WAVES 4             // waves per block
#define BLOCK (WAVES * 64)  // 256
#define QPB (QPW * WAVES)   // 32 queries per block
#define SLABS 8             // point-dimension split (parallelism): 256x8 = 2048 blocks
#define TILE 1024           // points staged per LDS tile (16 KB)

// Each block: 32 queries x one slab of N/SLABS points. Stages raw AoS points
// into LDS as (x,y,z,p2); hits appended straight into the output arrays via
// global atomics (order fixed up by finalize_kernel).
__global__ __launch_bounds__(BLOCK, 6) void search_kernel(
    const float* __restrict__ pts, const float* __restrict__ queries,
    const float* __restrict__ radius_p, float* __restrict__ out_idx,
    float* __restrict__ out_dist, int* __restrict__ counts, int N, int M) {
  __shared__ float4 tile[TILE];
  const int tid = threadIdx.x;
  const int lane = tid & 63;
  const int wave = tid >> 6;
  const float r = radius_p[0];
  const float rr = r * r;
  const int qbase = (blockIdx.x * WAVES + wave) * QPW;
  const int slab = (N + SLABS - 1) / SLABS;
  const int sb = blockIdx.y * slab;
  const int se = min(N, sb + slab);

  float qx[QPW], qy[QPW], qz[QPW], q2[QPW];
#pragma unroll
  for (int g = 0; g < QPW; ++g) {
    int q = qbase + g;
    if (q < M) {
      float x = queries[q * 3 + 0];
      float y = queries[q * 3 + 1];
      float z = queries[q * 3 + 2];
      qx[g] = x; qy[g] = y; qz[g] = z;
      q2[g] = (x * x + y * y) + z * z;  // numpy sum order, no fma
    } else {
      qx[g] = 0.f; qy[g] = 0.f; qz[g] = 0.f;
      q2[g] = INFINITY;  // d2 = INF -> never a hit
    }
  }

  for (int base = sb; base < se; base += TILE) {
    for (int i = tid; i < TILE; i += BLOCK) {
      int p = base + i;
      float x = 0.f, y = 0.f, z = 0.f, p2 = INFINITY;  // pad -> never a hit
      if (p < se) {
        x = pts[p * 3 + 0];
        y = pts[p * 3 + 1];
        z = pts[p * 3 + 2];
        p2 = (x * x + y * y) + z * z;  // numpy sum order, no fma
      }
      tile[i] = make_float4(x, y, z, p2);
    }
    __syncthreads();
#pragma unroll 2
    for (int it = 0; it < TILE / 64; ++it) {
      int j = it * 64 + lane;
      float4 p = tile[j];
      float d2v[QPW];
      bool hit[QPW];
      bool any = false;
#pragma unroll
      for (int g = 0; g < QPW; ++g) {
        // fma chain x->y->z (same as passing round-2 kernel).
        float dot = fmaf(p.z, qz[g], fmaf(p.y, qy[g], p.x * qx[g]));
        float s = q2[g] + p.w;
        // fmaf(dot,-2,s) bit-identical to s - 2.0f*dot (2*dot exact).
        float d2 = fmaf(dot, -2.0f, s);
        d2v[g] = d2;
        // Unclamped membership == clamped membership (negatives still <= rr).
        hit[g] = (d2 <= rr);
        any = any | hit[g];
      }
      if (__builtin_expect(any, 0)) {  // taken on ~10% of wave-iterations
#pragma unroll
        for (int g = 0; g < QPW; ++g)
          if (hit[g]) {
            int q = qbase + g;
            int pos = atomicAdd(&counts[q], 1);
            if (pos < KCAP) {
              out_dist[q * KCAP + pos] = fmaxf(d2v[g], 0.0f);  // clamp on output
              out_idx[q * KCAP + pos] = (float)(base + j);
            }
          }
      }
    }
    __syncthreads();
  }
}

// Blocks 0..nsort-1: one wave per query (8 queries/wave) bitonic-sorts the
// <=64 candidates by (d2, idx) — matches jax.lax.top_k stability — and
// finalizes padding. Block nsort: shuffle-based scan builds row_splits.
__global__ __launch_bounds__(256) void finalize_kernel(
    float* __restrict__ out_idx, float* __restrict__ out_dist,
    const int* __restrict__ counts, float* __restrict__ rs, int M) {
  const int b = blockIdx.x;
  const int nsort = gridDim.x - 1;
  const int tid = threadIdx.x;
  const int lane = tid & 63;
  const int wave = tid >> 6;

  if (b < nsort) {
#pragma unroll 1
    for (int g = 0; g < QPW; ++g) {
      int q = (b * WAVES + wave) * QPW + g;
      if (q >= M) break;
      int c = counts[q];
      int c64 = c < KCAP ? c : KCAP;
      float d2 = (lane < c64) ? out_dist[q * KCAP + lane] : INFINITY;
      int idx = (lane < c64) ? (int)out_idx[q * KCAP + lane] : 0x7fffffff;
      for (int k = 2; k <= 64; k <<= 1) {
        for (int jj = k >> 1; jj > 0; jj >>= 1) {
          float od2 = __shfl_xor(d2, jj);
          int oidx = __shfl_xor(idx, jj);
          bool up = ((lane & k) == 0);
          bool lower = ((lane & jj) == 0);
          bool takeMin = (lower == up);
          bool oLess = (od2 < d2) || (od2 == d2 && oidx < idx);
          bool take = takeMin ? oLess : !oLess;
          if (take) { d2 = od2; idx = oidx; }
        }
      }
      out_idx[q * KCAP + lane] = (lane < c64) ? (float)idx : -1.0f;
      out_dist[q * KCAP + lane] = (lane < c64) ? d2 : 0.0f;
    }
  } else {
    // Scan block: 256 threads x 32 counts each.
    __shared__ int wsum[WAVES];
    const int base = tid * 32;
    int s = 0;
#pragma unroll 4
    for (int j = 0; j < 32; ++j) {
      int i = base + j;
      int c = (i < M) ? counts[i] : 0;
      s += (c < KCAP ? c : KCAP);
    }
    int pre = s;  // wave-inclusive scan
    for (int off = 1; off < 64; off <<= 1) {
      int v = __shfl_up(pre, off);
      if (lane >= off) pre += v;
    }
    if (lane == 63) wsum[wave] = pre;
    __syncthreads();
    int woff = 0;
    for (int w = 0; w < wave; ++w) woff += wsum[w];
    int run = woff + pre - s;  // exclusive prefix for this thread's chunk
    if (tid == 0) rs[0] = 0.0f;
#pragma unroll 4
    for (int j = 0; j < 32; ++j) {
      int i = base + j;
      if (i < M) {
        int c = counts[i];
        run += (c < KCAP ? c : KCAP);
        rs[1 + i] = (float)run;
      }
    }
  }
}

extern "C" void kernel_launch(void* const* d_in, const int* in_sizes, int n_in,
                              void* d_out, int out_size, void* d_ws, size_t ws_size,
                              hipStream_t stream) {
  const float* points = (const float*)d_in[0];
  const float* queries = (const float*)d_in[1];
  const float* radius = (const float*)d_in[2];
  const int N = in_sizes[0] / 3;  // 16384
  const int M = in_sizes[1] / 3;  // 8192

  float* out = (float*)d_out;
  float* out_idx = out;                    // [M, 64]
  float* out_rs = out + (size_t)M * KCAP;  // [M+1]
  float* out_dist = out_rs + (M + 1);      // [M, 64]
  int* counts = (int*)d_ws;                // [M] scratch

  hipMemsetAsync(counts, 0, (size_t)M * sizeof(int), stream);

  dim3 grid((M + QPB - 1) / QPB, SLABS);  // 256 x 8 = 2048 blocks
  search_kernel<<<grid, BLOCK, 0, stream>>>(points, queries, radius, out_idx,
                                            out_dist, counts, N, M);

  const int nsort = (M + QPB - 1) / QPB;  // 256 sort blocks + 1 scan block
  finalize_kernel<<<nsort + 1, 256, 0, stream>>>(out_idx, out_dist, counts,
                                                 out_rs, M);
}